// Round 17
// baseline (617.436 us; speedup 1.0000x reference)
//
#include <hip/hip_runtime.h>
#include <hip/hip_bf16.h>

typedef __attribute__((ext_vector_type(8))) short bfrag_t;   // 8 bf16 (4 VGPRs)
typedef __attribute__((ext_vector_type(4))) float accum_t;   // 4 f32
typedef __attribute__((ext_vector_type(8))) unsigned short us8_t;

static_assert(sizeof(bfrag_t) == 16, "frag size");

static constexpr int M_NODES = 50000;
static constexpr int E_EDGES = 156000;
static constexpr int MT256   = 196;              // ceil(50000/256)
static constexpr int MT128   = 391;              // ceil(50000/128)
static constexpr int M_PAD   = MT256 * 256;      // 50176 (zero-padded rows)

// ---- manual RNE f32 -> bf16 ----
__device__ __forceinline__ unsigned short f2bf(float f) {
  unsigned int u = __float_as_uint(f);
  u = (u + 0x7FFFu + ((u >> 16) & 1u)) >> 16;
  return (unsigned short)u;
}
__device__ __forceinline__ float bf2f(unsigned short u) {
  return __uint_as_float(((unsigned int)u) << 16);
}

__device__ __forceinline__ void gll16(const unsigned short* g, unsigned short* l) {
  __builtin_amdgcn_global_load_lds(
      (const __attribute__((address_space(1))) void*)g,
      (__attribute__((address_space(3))) void*)l,
      16, 0, 0);
}

// ---- packed bf16x2 atomic add (HW instruction if available, CAS fallback) ----
typedef __attribute__((ext_vector_type(2))) short s2v;
__device__ __forceinline__ void agg_atomic_add(unsigned int* p, unsigned int zv) {
#if __has_builtin(__builtin_amdgcn_global_atomic_fadd_v2bf16)
  s2v v;
  __builtin_memcpy(&v, &zv, 4);
  __builtin_amdgcn_global_atomic_fadd_v2bf16(
      (__attribute__((address_space(1))) s2v*)p, v);
#else
  unsigned int old = *p, assumed;
  do {
    assumed = old;
    float lo = bf2f((unsigned short)(assumed & 0xffffu)) +
               bf2f((unsigned short)(zv & 0xffffu));
    float hi = bf2f((unsigned short)(assumed >> 16)) +
               bf2f((unsigned short)(zv >> 16));
    unsigned int nv = (unsigned int)f2bf(lo) | ((unsigned int)f2bf(hi) << 16);
    old = atomicCAS(p, assumed, nv);
  } while (old != assumed);
#endif
}

// ---- weight prep, K-MAJOR-8 (R13-validated) ----
__global__ void cast_w_kernel(const float* __restrict__ Wself,
                              const float* __restrict__ W1,
                              const float* __restrict__ W2,
                              const float* __restrict__ b2,
                              unsigned short* __restrict__ Wt1k,
                              unsigned short* __restrict__ Wt2k,
                              float* __restrict__ bias2) {
  int idx = blockIdx.x * 256 + threadIdx.x;
  if (idx < 1048576) {                       // Wt1k: idx = (kcg*2048 + n)*8 + j
    int j   = idx & 7;
    int n   = (idx >> 3) & 2047;
    int kcg = idx >> 14;
    int k   = kcg * 8 + j;
    float v = (n < 512)
        ? Wself[k * 512 + n]
        : W1[(size_t)((n - 512) >> 9) * 262144 + k * 512 + ((n - 512) & 511)];
    Wt1k[idx] = f2bf(v);
  } else if (idx < 1835008) {                // Wt2k: j2 = (kcg*512 + n)*8 + j
    int j2  = idx - 1048576;
    int j   = j2 & 7;
    int n   = (j2 >> 3) & 511;
    int kcg = j2 >> 12;
    int kk  = kcg * 8 + j;                   // 0..1535
    Wt2k[j2] = f2bf(W2[(size_t)(kk >> 9) * 262144 + (size_t)(kk & 511) * 512 + n]);
  } else if (idx < 1835520) {                // bias2
    int c = idx - 1835008;
    bias2[c] = b2[c] + b2[512 + c] + b2[1024 + c];
  }
}

// ---- cast+transpose x -> xk[kc(64)][row(M_PAD)][8] bf16 (R13-validated) ----
__global__ __launch_bounds__(256) void cast_xk_kernel(const float* __restrict__ x,
                                                      unsigned short* __restrict__ xk) {
  __shared__ unsigned short T[32][520];
  const int b   = blockIdx.x;
  const int tid = threadIdx.x;
  for (int j = 0; j < 16; ++j) {
    int idx = j * 256 + tid;
    int row = idx >> 7, c4 = idx & 127;
    int grow = b * 32 + row;
    float4 v = (grow < M_NODES) ? ((const float4*)(x + (size_t)grow * 512))[c4]
                                : make_float4(0.f, 0.f, 0.f, 0.f);
    unsigned short* t = &T[row][c4 * 4];
    t[0] = f2bf(v.x); t[1] = f2bf(v.y); t[2] = f2bf(v.z); t[3] = f2bf(v.w);
  }
  __syncthreads();
  for (int j = 0; j < 8; ++j) {
    int idx = j * 256 + tid;
    int kc = idx >> 5, row = idx & 31;
    *(us8_t*)&xk[((size_t)kc * M_PAD + b * 32 + row) * 8] = *(const us8_t*)&T[row][kc * 8];
  }
}

// ---- fused scatter, all relations, packed bf16 atomics (R8-validated) ----
__global__ void scatter_all_kernel(const unsigned short* __restrict__ Z,
                                   const int* __restrict__ ei,
                                   const int* __restrict__ et,
                                   unsigned short* __restrict__ agg) {
  int e    = blockIdx.x * 4 + (threadIdx.x >> 6);
  int lane = threadIdx.x & 63;
  if (e >= E_EDGES) return;
  int rel = et[e];
  int src = ei[e];
  int dst = ei[E_EDGES + e];
  const unsigned int* zs = (const unsigned int*)(Z + (size_t)src * 1536 + rel * 512);
  unsigned int* ad = (unsigned int*)(agg + (size_t)dst * 1536 + rel * 512);
  unsigned int v[4];
#pragma unroll
  for (int j = 0; j < 4; ++j) v[j] = zs[j * 64 + lane];
#pragma unroll
  for (int j = 0; j < 4; ++j) agg_atomic_add(ad + j * 64 + lane, v[j]);
}

// ---- relu + TRANSPOSE: Zk[kc][M_PAD][8] = relu(agg + b1), pad rows = 0 ----
__global__ __launch_bounds__(256) void relu_t_kernel(
    const unsigned short* __restrict__ agg,
    const float* __restrict__ b1,            // [1536] flat
    unsigned short* __restrict__ Zk) {
  __shared__ unsigned short T[16][1544];
  const int b   = blockIdx.x;
  const int tid = threadIdx.x;
#pragma unroll
  for (int j = 0; j < 12; ++j) {
    int idx = j * 256 + tid;
    int row = idx / 192, cc = idx % 192;
    int grow = b * 16 + row;
    us8_t o;
    if (grow < M_NODES) {
      us8_t a = ((const us8_t*)agg)[(size_t)grow * 192 + cc];
      const float* bb = b1 + cc * 8;
#pragma unroll
      for (int q = 0; q < 8; ++q)
        o[q] = f2bf(fmaxf(bf2f((unsigned short)a[q]) + bb[q], 0.f));
    } else {
#pragma unroll
      for (int q = 0; q < 8; ++q) o[q] = 0;
    }
    *(us8_t*)&T[row][cc * 8] = o;
  }
  __syncthreads();
#pragma unroll
  for (int j = 0; j < 12; ++j) {
    int idx = j * 256 + tid;
    int kc = idx >> 4, row = idx & 15;
    *(us8_t*)&Zk[((size_t)kc * M_PAD + b * 16 + row) * 8] = *(const us8_t*)&T[row][kc * 8];
  }
}

// ====== G1: 8-wave 256x128, BK=32, 3-buf ring; A,B K-MAJOR (R13/R14/R16) =====
__global__ __launch_bounds__(512, 4) void gemm1_kernel(
    const unsigned short* __restrict__ Ak,   // xk [64][M_PAD][8]
    const unsigned short* __restrict__ Bk,   // Wt1k [64][2048][8]
    float* __restrict__ outF,
    unsigned short* __restrict__ outB,
    unsigned short* __restrict__ aggB,
    const float* __restrict__ biasF) {
  constexpr int NT = 16, NTC = 16;
  __shared__ alignas(16) unsigned short L[3][12288];  // 72 KB
  const int tid  = threadIdx.x;
  const int lane = tid & 63;
  const int wid  = tid >> 6;
  const int wr   = wid >> 1;
  const int wn   = wid & 1;
  const int fr   = lane & 15;
  const int kcl  = lane >> 4;

  constexpr int nwg = MT256 * NTC;
  constexpr int q   = nwg / 8;
  const int orig = blockIdx.x;
  const int swz  = (orig & 7) * q + (orig >> 3);
  const int tileM = (swz / NTC) * 256;
  const int tileN = (swz % NTC) * 128;

  accum_t acc[4][4] = {};

  const unsigned short* gA = Ak + ((size_t)(tid >> 8) * M_PAD + tileM + (tid & 255)) * 8;
  const unsigned short* gB = Bk + ((size_t)(tid >> 7) * 2048 + tileN + (tid & 127)) * 8;
  constexpr size_t AKT = (size_t)4 * M_PAD * 8;
  constexpr size_t A2  = (size_t)2 * M_PAD * 8;
  constexpr size_t BKT = (size_t)4 * 2048 * 8;

#define STG(buf, kt) do {                                            \
    gll16(gA + (size_t)(kt) * AKT,      &L[buf][tid * 8]);           \
    gll16(gA + (size_t)(kt) * AKT + A2, &L[buf][tid * 8 + 4096]);    \
    gll16(gB + (size_t)(kt) * BKT,      &L[buf][8192 + tid * 8]);    \
  } while (0)

  const int aoff = kcl * 2048 + (wr * 64 + fr) * 8;
  const int boff = 8192 + kcl * 1024 + (wn * 64 + fr) * 8;

  STG(0, 0); STG(1, 1);

  for (int kt = 0; kt < NT; ++kt) {
    if (kt + 1 < NT) asm volatile("s_waitcnt vmcnt(3)" ::: "memory");
    else             asm volatile("s_waitcnt vmcnt(0)" ::: "memory");
    __builtin_amdgcn_s_barrier();

    const unsigned short* Ls = &L[kt % 3][0];
    bfrag_t b[4], a[4];
#pragma unroll
    for (int nf = 0; nf < 4; ++nf)
      b[nf] = *(const bfrag_t*)(Ls + boff + nf * 128);
#pragma unroll
    for (int mf = 0; mf < 4; ++mf)
      a[mf] = *(const bfrag_t*)(Ls + aoff + mf * 128);
    if (kt + 2 < NT) STG((kt + 2) % 3, kt + 2);
    __builtin_amdgcn_s_setprio(1);
#pragma unroll
    for (int mf = 0; mf < 4; ++mf)
#pragma unroll
      for (int nf = 0; nf < 4; ++nf)
        acc[mf][nf] = __builtin_amdgcn_mfma_f32_16x16x32_bf16(a[mf], b[nf], acc[mf][nf], 0, 0, 0);
    __builtin_amdgcn_s_setprio(0);
  }
#undef STG

  __syncthreads();   // L reusable as epilogue scratch

  const int rq = lane >> 4;
  if (tileN >= 512) {
    unsigned short* Wld = &L[0][0] + wid * 4608;   // 64 x 72 u16, wave-private
#pragma unroll
    for (int mf = 0; mf < 4; ++mf)
#pragma unroll
      for (int nf = 0; nf < 4; ++nf)
#pragma unroll
        for (int p = 0; p < 4; ++p)
          Wld[(mf * 16 + rq * 4 + p) * 72 + nf * 16 + fr] = f2bf(acc[mf][nf][p]);
    const int r8 = lane >> 3;
    const int ch = lane & 7;
    const size_t zc = (size_t)(tileN - 512) + wn * 64 + ch * 8;
#pragma unroll
    for (int pass = 0; pass < 8; ++pass) {
      const int lrow = pass * 8 + r8;
      const int grow = tileM + wr * 64 + lrow;
      us8_t v = *(const us8_t*)&Wld[lrow * 72 + ch * 8];
      if (grow < M_NODES) {
        *(us8_t*)&outB[(size_t)grow * 1536 + zc] = v;
        *(us8_t*)&aggB[(size_t)grow * 1536 + zc] = v;   // agg init = Z (dual)
      }
    }
  } else {
#pragma unroll
    for (int nf = 0; nf < 4; ++nf) {
      const int col = tileN + wn * 64 + nf * 16 + fr;
      const float bv = biasF[col];
#pragma unroll
      for (int mf = 0; mf < 4; ++mf) {
        const int rbase = tileM + wr * 64 + mf * 16 + rq * 4;
#pragma unroll
        for (int p = 0; p < 4; ++p) {
          const int row = rbase + p;
          if (row < M_NODES)
            outF[(size_t)row * 512 + col] = acc[mf][nf][p] + bv;
        }
      }
    }
  }
}

// ====== G2: 4-wave 128x128, BK=32, 3-buf ring, 3 blocks/CU; A,B K-MAJOR ======
// Packing fix: 1564 blocks / 768 slots = 2.04 -> 3 gens x t/2 vs 2 gens x t.
__global__ __launch_bounds__(256, 3) void gemm2_kernel(
    const unsigned short* __restrict__ Ak,   // Zk [192][M_PAD][8]
    const unsigned short* __restrict__ Bk,   // Wt2k [192][512][8]
    float* __restrict__ outF,
    const float* __restrict__ bias) {
  constexpr int NT = 48, NTC = 4;
  __shared__ alignas(16) unsigned short L[3][8192];  // 48 KB
  const int tid  = threadIdx.x;
  const int lane = tid & 63;
  const int wid  = tid >> 6;    // 0..3
  const int wr   = wid >> 1;    // 0..1 : 64-row band
  const int wn   = wid & 1;     // 0..1 : 64-col band
  const int fr   = lane & 15;
  const int kcl  = lane >> 4;

  // bijective XCD swizzle, general form (1564 % 8 = 4)
  constexpr int nwg = MT128 * NTC;   // 1564
  constexpr int q   = nwg / 8;       // 195
  constexpr int rr  = nwg % 8;       // 4
  const int orig = blockIdx.x;
  const int xcd  = orig & 7;
  const int lid  = orig >> 3;
  const int swz  = (xcd < rr ? xcd * (q + 1) : rr * (q + 1) + (xcd - rr) * q) + lid;
  const int tileM = (swz / NTC) * 128;
  const int tileN = (swz % NTC) * 128;

  accum_t acc[4][4] = {};

  // staging: 4 gll16/thread/K-tile; kc_local = (tid>>7) + {0,2}; row/col = tid&127
  const unsigned short* gA = Ak + ((size_t)(tid >> 7) * M_PAD + tileM + (tid & 127)) * 8;
  const unsigned short* gB = Bk + ((size_t)(tid >> 7) * 512 + tileN + (tid & 127)) * 8;
  constexpr size_t AKT = (size_t)4 * M_PAD * 8;
  constexpr size_t A2  = (size_t)2 * M_PAD * 8;
  constexpr size_t BKT = (size_t)4 * 512 * 8;
  constexpr size_t B2  = (size_t)2 * 512 * 8;

#define STG(buf, kt) do {                                                \
    gll16(gA + (size_t)(kt) * AKT,      &L[buf][tid * 8]);               \
    gll16(gA + (size_t)(kt) * AKT + A2, &L[buf][tid * 8 + 2048]);        \
    gll16(gB + (size_t)(kt) * BKT,      &L[buf][4096 + tid * 8]);        \
    gll16(gB + (size_t)(kt) * BKT + B2, &L[buf][4096 + tid * 8 + 2048]); \
  } while (0)

  // frag offsets (u16 within buf): A [kc(4)][row(128)][8] at 0, B at 4096
  const int aoff = kcl * 1024 + (wr * 64 + fr) * 8;          // + mf*128
  const int boff = 4096 + kcl * 1024 + (wn * 64 + fr) * 8;   // + nf*128

  STG(0, 0); STG(1, 1);

  for (int kt = 0; kt < NT; ++kt) {
    if (kt + 1 < NT) asm volatile("s_waitcnt vmcnt(4)" ::: "memory");  // kt landed
    else             asm volatile("s_waitcnt vmcnt(0)" ::: "memory");
    __builtin_amdgcn_s_barrier();

    const unsigned short* Ls = &L[kt % 3][0];
    bfrag_t b[4], a[4];
#pragma unroll
    for (int nf = 0; nf < 4; ++nf)
      b[nf] = *(const bfrag_t*)(Ls + boff + nf * 128);
#pragma unroll
    for (int mf = 0; mf < 4; ++mf)
      a[mf] = *(const bfrag_t*)(Ls + aoff + mf * 128);
    if (kt + 2 < NT) STG((kt + 2) % 3, kt + 2);  // slot last read at kt-1: safe
    __builtin_amdgcn_s_setprio(1);
#pragma unroll
    for (int mf = 0; mf < 4; ++mf)
#pragma unroll
      for (int nf = 0; nf < 4; ++nf)
        acc[mf][nf] = __builtin_amdgcn_mfma_f32_16x16x32_bf16(a[mf], b[nf], acc[mf][nf], 0, 0, 0);
    __builtin_amdgcn_s_setprio(0);
  }
#undef STG

  const int rq = lane >> 4;
#pragma unroll
  for (int nf = 0; nf < 4; ++nf) {
    const int col = tileN + wn * 64 + nf * 16 + fr;
    const float bv = bias[col];
#pragma unroll
    for (int mf = 0; mf < 4; ++mf) {
      const int rbase = tileM + wr * 64 + mf * 16 + rq * 4;
#pragma unroll
      for (int p = 0; p < 4; ++p) {
        const int row = rbase + p;
        if (row < M_NODES)
          outF[(size_t)row * 512 + col] += acc[mf][nf][p] + bv;
      }
    }
  }
}

extern "C" void kernel_launch(void* const* d_in, const int* in_sizes, int n_in,
                              void* d_out, int out_size, void* d_ws, size_t ws_size,
                              hipStream_t stream) {
  const float* x     = (const float*)d_in[0];
  const int*   ei    = (const int*)d_in[1];
  const int*   et    = (const int*)d_in[2];
  const float* Wself = (const float*)d_in[3];
  const float* bself = (const float*)d_in[4];
  const float* W1    = (const float*)d_in[5];
  const float* b1    = (const float*)d_in[6];
  const float* W2    = (const float*)d_in[7];
  const float* b2    = (const float*)d_in[8];
  float* out = (float*)d_out;

  // ws layout:
  //   region1 [0, 153.6 MB): agg bf16 [M][1536]
  //   region2 [153.6, 307.2 MB): Z row-major (G1->scatter), then Zk k-major
  //   [307.2 MB +): Wt1k, Wt2k, bias2
  //   DUAL mode (ws >= 362.3 MB): xk [64][M_PAD][8] at 310.88 MB, disjoint
  //     from agg -> G1 dual-writes agg directly, copy eliminated.
  //   Fallback: xk aliases region1 (R14), agg seeded via D2D copy after G1.
  char* ws = (char*)d_ws;
  unsigned short* agg   = (unsigned short*)ws;
  unsigned short* Z     = (unsigned short*)(ws + 153600000);
  unsigned short* Zk    = (unsigned short*)(ws + 153600000);
  unsigned short* Wt1k  = (unsigned short*)(ws + 307200000);   // 2.1 MB
  unsigned short* Wt2k  = (unsigned short*)(ws + 309297152);   // 1.6 MB
  float*          bias2 = (float*)(ws + 310870016);            // 2 KB

  const bool dual = (ws_size >= (size_t)362260480);
  unsigned short* xk = dual ? (unsigned short*)(ws + 310880256)  // 51.4 MB
                            : (unsigned short*)ws;               // aliases agg

  cast_w_kernel<<<7171, 256, 0, stream>>>(Wself, W1, W2, b2, Wt1k, Wt2k, bias2);
  cast_xk_kernel<<<M_PAD / 32, 256, 0, stream>>>(x, xk);

  // G1: Y = x @ [W_self | W1cat]; Z (+agg when dual) written in epilogue.
  gemm1_kernel<<<MT256 * 16, 512, 0, stream>>>(xk, Wt1k, out, Z,
                                               dual ? agg : Z, bself);

  if (!dual) {
    hipMemcpyAsync(agg, Z, (size_t)M_NODES * 1536 * sizeof(unsigned short),
                   hipMemcpyDeviceToDevice, stream);
  }

  scatter_all_kernel<<<E_EDGES / 4, 256, 0, stream>>>(Z, ei, et, agg);
  relu_t_kernel<<<M_PAD / 16, 256, 0, stream>>>(agg, b1, Zk);

  // G2: out += h @ W2cat + bias2  (128^2, 4-wave, 3 blocks/CU packing fix)
  gemm2_kernel<<<MT128 * 4, 256, 0, stream>>>(Zk, Wt2k, out, bias2);
}

// Round 18
// 583.769 us; speedup vs baseline: 1.0577x; 1.0577x over previous
//
#include <hip/hip_runtime.h>
#include <hip/hip_bf16.h>

typedef __attribute__((ext_vector_type(8))) short bfrag_t;   // 8 bf16 (4 VGPRs)
typedef __attribute__((ext_vector_type(4))) float accum_t;   // 4 f32
typedef __attribute__((ext_vector_type(8))) unsigned short us8_t;

static_assert(sizeof(bfrag_t) == 16, "frag size");

static constexpr int M_NODES = 50000;
static constexpr int E_EDGES = 156000;
static constexpr int MT256   = 196;              // ceil(50000/256)
static constexpr int M_PAD   = MT256 * 256;      // 50176 (zero-padded rows)

// ---- manual RNE f32 -> bf16 ----
__device__ __forceinline__ unsigned short f2bf(float f) {
  unsigned int u = __float_as_uint(f);
  u = (u + 0x7FFFu + ((u >> 16) & 1u)) >> 16;
  return (unsigned short)u;
}
__device__ __forceinline__ float bf2f(unsigned short u) {
  return __uint_as_float(((unsigned int)u) << 16);
}

__device__ __forceinline__ void gll16(const unsigned short* g, unsigned short* l) {
  __builtin_amdgcn_global_load_lds(
      (const __attribute__((address_space(1))) void*)g,
      (__attribute__((address_space(3))) void*)l,
      16, 0, 0);
}

// ---- packed bf16x2 atomic add (HW instruction if available, CAS fallback) ----
typedef __attribute__((ext_vector_type(2))) short s2v;
__device__ __forceinline__ void agg_atomic_add(unsigned int* p, unsigned int zv) {
#if __has_builtin(__builtin_amdgcn_global_atomic_fadd_v2bf16)
  s2v v;
  __builtin_memcpy(&v, &zv, 4);
  __builtin_amdgcn_global_atomic_fadd_v2bf16(
      (__attribute__((address_space(1))) s2v*)p, v);
#else
  unsigned int old = *p, assumed;
  do {
    assumed = old;
    float lo = bf2f((unsigned short)(assumed & 0xffffu)) +
               bf2f((unsigned short)(zv & 0xffffu));
    float hi = bf2f((unsigned short)(assumed >> 16)) +
               bf2f((unsigned short)(zv >> 16));
    unsigned int nv = (unsigned int)f2bf(lo) | ((unsigned int)f2bf(hi) << 16);
    old = atomicCAS(p, assumed, nv);
  } while (old != assumed);
#endif
}

// ---- weight prep, K-MAJOR-8 (R13-validated) ----
__global__ void cast_w_kernel(const float* __restrict__ Wself,
                              const float* __restrict__ W1,
                              const float* __restrict__ W2,
                              const float* __restrict__ b2,
                              unsigned short* __restrict__ Wt1k,
                              unsigned short* __restrict__ Wt2k,
                              float* __restrict__ bias2) {
  int idx = blockIdx.x * 256 + threadIdx.x;
  if (idx < 1048576) {                       // Wt1k: idx = (kcg*2048 + n)*8 + j
    int j   = idx & 7;
    int n   = (idx >> 3) & 2047;
    int kcg = idx >> 14;
    int k   = kcg * 8 + j;
    float v = (n < 512)
        ? Wself[k * 512 + n]
        : W1[(size_t)((n - 512) >> 9) * 262144 + k * 512 + ((n - 512) & 511)];
    Wt1k[idx] = f2bf(v);
  } else if (idx < 1835008) {                // Wt2k: j2 = (kcg*512 + n)*8 + j
    int j2  = idx - 1048576;
    int j   = j2 & 7;
    int n   = (j2 >> 3) & 511;
    int kcg = j2 >> 12;
    int kk  = kcg * 8 + j;                   // 0..1535
    Wt2k[j2] = f2bf(W2[(size_t)(kk >> 9) * 262144 + (size_t)(kk & 511) * 512 + n]);
  } else if (idx < 1835520) {                // bias2
    int c = idx - 1835008;
    bias2[c] = b2[c] + b2[512 + c] + b2[1024 + c];
  }
}

// ---- cast+transpose x -> xk[kc(64)][row(M_PAD)][8] bf16 (R13-validated) ----
__global__ __launch_bounds__(256) void cast_xk_kernel(const float* __restrict__ x,
                                                      unsigned short* __restrict__ xk) {
  __shared__ unsigned short T[32][520];
  const int b   = blockIdx.x;
  const int tid = threadIdx.x;
  for (int j = 0; j < 16; ++j) {
    int idx = j * 256 + tid;
    int row = idx >> 7, c4 = idx & 127;
    int grow = b * 32 + row;
    float4 v = (grow < M_NODES) ? ((const float4*)(x + (size_t)grow * 512))[c4]
                                : make_float4(0.f, 0.f, 0.f, 0.f);
    unsigned short* t = &T[row][c4 * 4];
    t[0] = f2bf(v.x); t[1] = f2bf(v.y); t[2] = f2bf(v.z); t[3] = f2bf(v.w);
  }
  __syncthreads();
  for (int j = 0; j < 8; ++j) {
    int idx = j * 256 + tid;
    int kc = idx >> 5, row = idx & 31;
    *(us8_t*)&xk[((size_t)kc * M_PAD + b * 32 + row) * 8] = *(const us8_t*)&T[row][kc * 8];
  }
}

// ---- fused scatter, all relations, packed bf16 atomics (R8-validated) ----
__global__ void scatter_all_kernel(const unsigned short* __restrict__ Z,
                                   const int* __restrict__ ei,
                                   const int* __restrict__ et,
                                   unsigned short* __restrict__ agg) {
  int e    = blockIdx.x * 4 + (threadIdx.x >> 6);
  int lane = threadIdx.x & 63;
  if (e >= E_EDGES) return;
  int rel = et[e];
  int src = ei[e];
  int dst = ei[E_EDGES + e];
  const unsigned int* zs = (const unsigned int*)(Z + (size_t)src * 1536 + rel * 512);
  unsigned int* ad = (unsigned int*)(agg + (size_t)dst * 1536 + rel * 512);
  unsigned int v[4];
#pragma unroll
  for (int j = 0; j < 4; ++j) v[j] = zs[j * 64 + lane];
#pragma unroll
  for (int j = 0; j < 4; ++j) agg_atomic_add(ad + j * 64 + lane, v[j]);
}

// ---- relu + TRANSPOSE: Zk[kc][M_PAD][8] = relu(agg + b1), pad rows = 0 ----
__global__ __launch_bounds__(256) void relu_t_kernel(
    const unsigned short* __restrict__ agg,
    const float* __restrict__ b1,            // [1536] flat
    unsigned short* __restrict__ Zk) {
  __shared__ unsigned short T[16][1544];
  const int b   = blockIdx.x;
  const int tid = threadIdx.x;
#pragma unroll
  for (int j = 0; j < 12; ++j) {
    int idx = j * 256 + tid;
    int row = idx / 192, cc = idx % 192;
    int grow = b * 16 + row;
    us8_t o;
    if (grow < M_NODES) {
      us8_t a = ((const us8_t*)agg)[(size_t)grow * 192 + cc];
      const float* bb = b1 + cc * 8;
#pragma unroll
      for (int q = 0; q < 8; ++q)
        o[q] = f2bf(fmaxf(bf2f((unsigned short)a[q]) + bb[q], 0.f));
    } else {
#pragma unroll
      for (int q = 0; q < 8; ++q) o[q] = 0;
    }
    *(us8_t*)&T[row][cc * 8] = o;
  }
  __syncthreads();
#pragma unroll
  for (int j = 0; j < 12; ++j) {
    int idx = j * 256 + tid;
    int kc = idx >> 4, row = idx & 15;
    *(us8_t*)&Zk[((size_t)kc * M_PAD + b * 16 + row) * 8] = *(const us8_t*)&T[row][kc * 8];
  }
}

// ====== G1: 8-wave 256x128, BK=32, 3-buf ring; A,B K-MAJOR (R13/R14/R16) =====
__global__ __launch_bounds__(512, 4) void gemm1_kernel(
    const unsigned short* __restrict__ Ak,   // xk [64][M_PAD][8]
    const unsigned short* __restrict__ Bk,   // Wt1k [64][2048][8]
    float* __restrict__ outF,
    unsigned short* __restrict__ outB,
    unsigned short* __restrict__ aggB,
    const float* __restrict__ biasF) {
  constexpr int NT = 16, NTC = 16;
  __shared__ alignas(16) unsigned short L[3][12288];  // 72 KB
  const int tid  = threadIdx.x;
  const int lane = tid & 63;
  const int wid  = tid >> 6;
  const int wr   = wid >> 1;
  const int wn   = wid & 1;
  const int fr   = lane & 15;
  const int kcl  = lane >> 4;

  constexpr int nwg = MT256 * NTC;
  constexpr int q   = nwg / 8;
  const int orig = blockIdx.x;
  const int swz  = (orig & 7) * q + (orig >> 3);
  const int tileM = (swz / NTC) * 256;
  const int tileN = (swz % NTC) * 128;

  accum_t acc[4][4] = {};

  const unsigned short* gA = Ak + ((size_t)(tid >> 8) * M_PAD + tileM + (tid & 255)) * 8;
  const unsigned short* gB = Bk + ((size_t)(tid >> 7) * 2048 + tileN + (tid & 127)) * 8;
  constexpr size_t AKT = (size_t)4 * M_PAD * 8;
  constexpr size_t A2  = (size_t)2 * M_PAD * 8;
  constexpr size_t BKT = (size_t)4 * 2048 * 8;

#define STG(buf, kt) do {                                            \
    gll16(gA + (size_t)(kt) * AKT,      &L[buf][tid * 8]);           \
    gll16(gA + (size_t)(kt) * AKT + A2, &L[buf][tid * 8 + 4096]);    \
    gll16(gB + (size_t)(kt) * BKT,      &L[buf][8192 + tid * 8]);    \
  } while (0)

  const int aoff = kcl * 2048 + (wr * 64 + fr) * 8;
  const int boff = 8192 + kcl * 1024 + (wn * 64 + fr) * 8;

  STG(0, 0); STG(1, 1);

  for (int kt = 0; kt < NT; ++kt) {
    if (kt + 1 < NT) asm volatile("s_waitcnt vmcnt(3)" ::: "memory");
    else             asm volatile("s_waitcnt vmcnt(0)" ::: "memory");
    __builtin_amdgcn_s_barrier();

    const unsigned short* Ls = &L[kt % 3][0];
    bfrag_t b[4], a[4];
#pragma unroll
    for (int nf = 0; nf < 4; ++nf)
      b[nf] = *(const bfrag_t*)(Ls + boff + nf * 128);
#pragma unroll
    for (int mf = 0; mf < 4; ++mf)
      a[mf] = *(const bfrag_t*)(Ls + aoff + mf * 128);
    if (kt + 2 < NT) STG((kt + 2) % 3, kt + 2);
    __builtin_amdgcn_s_setprio(1);
#pragma unroll
    for (int mf = 0; mf < 4; ++mf)
#pragma unroll
      for (int nf = 0; nf < 4; ++nf)
        acc[mf][nf] = __builtin_amdgcn_mfma_f32_16x16x32_bf16(a[mf], b[nf], acc[mf][nf], 0, 0, 0);
    __builtin_amdgcn_s_setprio(0);
  }
#undef STG

  __syncthreads();   // L reusable as epilogue scratch

  const int rq = lane >> 4;
  if (tileN >= 512) {
    unsigned short* Wld = &L[0][0] + wid * 4608;   // 64 x 72 u16, wave-private
#pragma unroll
    for (int mf = 0; mf < 4; ++mf)
#pragma unroll
      for (int nf = 0; nf < 4; ++nf)
#pragma unroll
        for (int p = 0; p < 4; ++p)
          Wld[(mf * 16 + rq * 4 + p) * 72 + nf * 16 + fr] = f2bf(acc[mf][nf][p]);
    const int r8 = lane >> 3;
    const int ch = lane & 7;
    const size_t zc = (size_t)(tileN - 512) + wn * 64 + ch * 8;
#pragma unroll
    for (int pass = 0; pass < 8; ++pass) {
      const int lrow = pass * 8 + r8;
      const int grow = tileM + wr * 64 + lrow;
      us8_t v = *(const us8_t*)&Wld[lrow * 72 + ch * 8];
      if (grow < M_NODES) {
        *(us8_t*)&outB[(size_t)grow * 1536 + zc] = v;
        *(us8_t*)&aggB[(size_t)grow * 1536 + zc] = v;   // agg init = Z (dual)
      }
    }
  } else {
#pragma unroll
    for (int nf = 0; nf < 4; ++nf) {
      const int col = tileN + wn * 64 + nf * 16 + fr;
      const float bv = biasF[col];
#pragma unroll
      for (int mf = 0; mf < 4; ++mf) {
        const int rbase = tileM + wr * 64 + mf * 16 + rq * 4;
#pragma unroll
        for (int p = 0; p < 4; ++p) {
          const int row = rbase + p;
          if (row < M_NODES)
            outF[(size_t)row * 512 + col] = acc[mf][nf][p] + bv;
        }
      }
    }
  }
}

// ====== G2: 8-wave 256x128, BK=32; A,B K-MAJOR; 3-buf ring (R14/R16, 161us) ==
__global__ __launch_bounds__(512, 4) void gemm2_kernel(
    const unsigned short* __restrict__ Ak,   // Zk [192][M_PAD][8]
    const unsigned short* __restrict__ Bk,   // Wt2k [192][512][8]
    float* __restrict__ outF,
    const float* __restrict__ bias) {
  constexpr int NT = 48, NTC = 4;
  __shared__ alignas(16) unsigned short L[3][12288];  // 72 KB
  const int tid  = threadIdx.x;
  const int lane = tid & 63;
  const int wid  = tid >> 6;
  const int wr   = wid >> 1;
  const int wn   = wid & 1;
  const int fr   = lane & 15;
  const int kcl  = lane >> 4;

  constexpr int nwg = MT256 * NTC;
  constexpr int q   = nwg / 8;
  const int orig = blockIdx.x;
  const int swz  = (orig & 7) * q + (orig >> 3);
  const int tileM = (swz / NTC) * 256;
  const int tileN = (swz % NTC) * 128;

  accum_t acc[4][4] = {};

  const unsigned short* gA = Ak + ((size_t)(tid >> 8) * M_PAD + tileM + (tid & 255)) * 8;
  const unsigned short* gB = Bk + ((size_t)(tid >> 7) * 512 + tileN + (tid & 127)) * 8;
  constexpr size_t AKT = (size_t)4 * M_PAD * 8;
  constexpr size_t A2  = (size_t)2 * M_PAD * 8;
  constexpr size_t BKT = (size_t)4 * 512 * 8;

#define STG(buf, kt) do {                                            \
    gll16(gA + (size_t)(kt) * AKT,      &L[buf][tid * 8]);           \
    gll16(gA + (size_t)(kt) * AKT + A2, &L[buf][tid * 8 + 4096]);    \
    gll16(gB + (size_t)(kt) * BKT,      &L[buf][8192 + tid * 8]);    \
  } while (0)

  const int aoff = kcl * 2048 + (wr * 64 + fr) * 8;
  const int boff = 8192 + kcl * 1024 + (wn * 64 + fr) * 8;

  STG(0, 0); STG(1, 1);

  for (int kt = 0; kt < NT; ++kt) {
    if (kt + 1 < NT) asm volatile("s_waitcnt vmcnt(3)" ::: "memory");
    else             asm volatile("s_waitcnt vmcnt(0)" ::: "memory");
    __builtin_amdgcn_s_barrier();

    const unsigned short* Ls = &L[kt % 3][0];
    bfrag_t b[4], a[4];
#pragma unroll
    for (int nf = 0; nf < 4; ++nf)
      b[nf] = *(const bfrag_t*)(Ls + boff + nf * 128);
#pragma unroll
    for (int mf = 0; mf < 4; ++mf)
      a[mf] = *(const bfrag_t*)(Ls + aoff + mf * 128);
    if (kt + 2 < NT) STG((kt + 2) % 3, kt + 2);
    __builtin_amdgcn_s_setprio(1);
#pragma unroll
    for (int mf = 0; mf < 4; ++mf)
#pragma unroll
      for (int nf = 0; nf < 4; ++nf)
        acc[mf][nf] = __builtin_amdgcn_mfma_f32_16x16x32_bf16(a[mf], b[nf], acc[mf][nf], 0, 0, 0);
    __builtin_amdgcn_s_setprio(0);
  }
#undef STG

  const int rq = lane >> 4;
#pragma unroll
  for (int nf = 0; nf < 4; ++nf) {
    const int col = tileN + wn * 64 + nf * 16 + fr;
    const float bv = bias[col];
#pragma unroll
    for (int mf = 0; mf < 4; ++mf) {
      const int rbase = tileM + wr * 64 + mf * 16 + rq * 4;
#pragma unroll
      for (int p = 0; p < 4; ++p) {
        const int row = rbase + p;
        if (row < M_NODES)
          outF[(size_t)row * 512 + col] += acc[mf][nf][p] + bv;
      }
    }
  }
}

extern "C" void kernel_launch(void* const* d_in, const int* in_sizes, int n_in,
                              void* d_out, int out_size, void* d_ws, size_t ws_size,
                              hipStream_t stream) {
  const float* x     = (const float*)d_in[0];
  const int*   ei    = (const int*)d_in[1];
  const int*   et    = (const int*)d_in[2];
  const float* Wself = (const float*)d_in[3];
  const float* bself = (const float*)d_in[4];
  const float* W1    = (const float*)d_in[5];
  const float* b1    = (const float*)d_in[6];
  const float* W2    = (const float*)d_in[7];
  const float* b2    = (const float*)d_in[8];
  float* out = (float*)d_out;

  // ws layout:
  //   region1 [0, 153.6 MB): agg bf16 [M][1536]
  //   region2 [153.6, 307.2 MB): Z row-major (G1->scatter), then Zk k-major
  //   [307.2 MB +): Wt1k, Wt2k, bias2
  //   DUAL mode (ws >= 362.3 MB): xk [64][M_PAD][8] at 310.88 MB, disjoint
  //     from agg -> G1 dual-writes agg directly, copy eliminated.
  //   Fallback: xk aliases region1 (R14), agg seeded via D2D copy after G1.
  char* ws = (char*)d_ws;
  unsigned short* agg   = (unsigned short*)ws;
  unsigned short* Z     = (unsigned short*)(ws + 153600000);
  unsigned short* Zk    = (unsigned short*)(ws + 153600000);
  unsigned short* Wt1k  = (unsigned short*)(ws + 307200000);   // 2.1 MB
  unsigned short* Wt2k  = (unsigned short*)(ws + 309297152);   // 1.6 MB
  float*          bias2 = (float*)(ws + 310870016);            // 2 KB

  const bool dual = (ws_size >= (size_t)362260480);
  unsigned short* xk = dual ? (unsigned short*)(ws + 310880256)  // 51.4 MB
                            : (unsigned short*)ws;               // aliases agg

  cast_w_kernel<<<7171, 256, 0, stream>>>(Wself, W1, W2, b2, Wt1k, Wt2k, bias2);
  cast_xk_kernel<<<M_PAD / 32, 256, 0, stream>>>(x, xk);

  // G1: Y = x @ [W_self | W1cat]; Z (+agg when dual) written in epilogue.
  gemm1_kernel<<<MT256 * 16, 512, 0, stream>>>(xk, Wt1k, out, Z,
                                               dual ? agg : Z, bself);

  if (!dual) {
    hipMemcpyAsync(agg, Z, (size_t)M_NODES * 1536 * sizeof(unsigned short),
                   hipMemcpyDeviceToDevice, stream);
  }

  scatter_all_kernel<<<E_EDGES / 4, 256, 0, stream>>>(Z, ei, et, agg);
  relu_t_kernel<<<M_PAD / 16, 256, 0, stream>>>(agg, b1, Zk);

  // G2: out += h @ W2cat + bias2  (3-buf ring, R14/R16-measured 161 us)
  gemm2_kernel<<<MT256 * 4, 512, 0, stream>>>(Zk, Wt2k, out, bias2);
}